// Round 1
// 143.518 us; speedup vs baseline: 1.0301x; 1.0301x over previous
//
#include <hip/hip_runtime.h>
#include <hip/hip_bf16.h>

#define NN 7936
#define EE 63488
#define CIN 5
#define WW 64
#define KK 8
#define H1C 64
#define H2C 16
#define T1 57            // 64-8+1
#define T2 50            // 57-8+1
#define FT (T1*H2C)      // 912 elems per node for xt (f16)

typedef _Float16 half8 __attribute__((ext_vector_type(8)));
typedef _Float16 half4 __attribute__((ext_vector_type(4)));
typedef float f32x4 __attribute__((ext_vector_type(4)));

// ---------------------------------------------------------------------------
__global__ void k_detect(const int* __restrict__ ei, int* __restrict__ flag) {
    if (threadIdx.x == 0 && blockIdx.x == 0) {
        int f = 1;
        for (int i = 0; i < 32; ++i) {
            if (ei[2 * i + 1] != 0) { f = 0; break; }
        }
        *flag = f;
    }
}

__device__ __forceinline__ int load_row(const int* ei, int f, int e) {
    return f ? ei[2 * e] : ei[e];
}
__device__ __forceinline__ int load_col(const int* ei, int f, int e) {
    return f ? ei[2 * (EE + e)] : ei[EE + e];
}

// ---------------------------------------------------------------------------
// Fused: per-destination degree atomics (blocks 0..247) + weight prep
// (blocks 248..347).
__global__ void k_deg_prep(const int* __restrict__ ei, const int* __restrict__ flag,
                           const float* __restrict__ ew,
                           float* __restrict__ deg, int* __restrict__ cnt,
                           const float* __restrict__ Wc2, _Float16* __restrict__ w2p,
                           const float* __restrict__ Wc1, _Float16* __restrict__ w1p,
                           const float* __restrict__ Wg, _Float16* __restrict__ wgp) {
    int b = blockIdx.x;
    if (b < EE / 256) {
        int e = b * 256 + threadIdx.x;
        int f = *flag;
        int c = load_col(ei, f, e);
        atomicAdd(&deg[c], ew[e]);
        atomicAdd(&cnt[c], 1);
        return;
    }
    int i = (b - EE / 256) * 256 + threadIdx.x;
    if (i < 16384) {
        // conv2 B-frags: slot=(s*4+lg)*128+nt*16+c, elem e
        int e = i & 7;
        int slot = i >> 3;
        int c  = slot & 15;
        int nt = (slot >> 4) & 7;
        int g  = (slot >> 7) & 3;
        int s  = (slot >> 9) & 3;
        int ci = g * 4 + (e >> 1);
        w2p[i] = (_Float16)Wc2[(nt * 16 + c) * 128 + ci * 8 + 2 * s + (e & 1)];
    } else if (i < 16384 + 8192) {
        // conv1 GEMM1 A-frags with sigma channel permutation
        int j = i - 16384;
        int e = j & 7;
        int m = (j >> 3) & 127;
        int slg = j >> 10;              // 0..7 = s*4+lg
        int ci = (slg >> 2) * 4 + (slg & 3);
        int hi = m >> 6;                // 0 = P, 1 = Q
        int mb = m & 63;
        int mt = mb >> 4, r = mb & 15;
        int sig = hi * 64 + 32 * (mt >> 1) + 8 * (r >> 2) + 4 * (mt & 1) + (r & 3);
        w1p[j] = (ci < CIN) ? (_Float16)Wc1[sig * (CIN * KK) + ci * KK + e]
                            : (_Float16)0.0f;
    } else if (i < 16384 + 8192 + 1024) {
        // conv1 GEMM2 B-frags (Wg)
        int j = i - 16384 - 8192;
        int e = j & 7;
        int f = (j >> 3) & 15;
        int slg = j >> 7;               // 0..7
        int c = (slg >> 2) * 32 + (slg & 3) * 8 + e;
        wgp[j] = (_Float16)Wg[c * H2C + f];
    }
}

__global__ void k_scan(const int* __restrict__ cnt, int* __restrict__ offs,
                       int* __restrict__ cursor) {
    __shared__ int part[1024];
    int tid = threadIdx.x;
    int base = tid * 8;
    int local[8];
    int s = 0;
#pragma unroll
    for (int j = 0; j < 8; ++j) {
        int idx = base + j;
        int v = (idx < NN) ? cnt[idx] : 0;
        local[j] = s;
        s += v;
    }
    part[tid] = s;
    __syncthreads();
    for (int d = 1; d < 1024; d <<= 1) {
        int v = 0;
        if (tid >= d) v = part[tid - d];
        __syncthreads();
        if (tid >= d) part[tid] += v;
        __syncthreads();
    }
    int ex = (tid > 0) ? part[tid - 1] : 0;
#pragma unroll
    for (int j = 0; j < 8; ++j) {
        int idx = base + j;
        if (idx < NN) {
            offs[idx] = ex + local[j];
            cursor[idx] = ex + local[j];
        }
    }
    if (tid == 1023) offs[NN] = part[1023];
}

// Bucket-fill: em[pos] = (src, dinv[src]*ew) — kills two loads + a rsqrt
// from the gather's dependent chain.
__global__ void k_fill(const int* __restrict__ ei, const int* __restrict__ flag,
                       const float* __restrict__ ew, const float* __restrict__ deg,
                       int* __restrict__ cursor, int2* __restrict__ em) {
    int e = blockIdx.x * blockDim.x + threadIdx.x;
    if (e >= EE) return;
    int f = *flag;
    int c = load_col(ei, f, e);
    int r = load_row(ei, f, e);
    int pos = atomicAdd(&cursor[c], 1);
    em[pos] = make_int2(r, __float_as_int(rsqrtf(deg[r] + 1.0f) * ew[e]));
}

// ---------------------------------------------------------------------------
// conv1, fully register-resident (zero LDS, zero barriers). Wave = 1 node.
// Stores xt as f16 [t][f], stride 912 halves (16B-aligned node base).
__global__ __launch_bounds__(256, 3) void k_conv1(
        const float* __restrict__ x, const _Float16* __restrict__ w1p,
        const float* __restrict__ b1, const _Float16* __restrict__ wgp,
        _Float16* __restrict__ xt) {
    int tid = threadIdx.x;
    int w = tid >> 6, lane = tid & 63;
    int lc = lane & 15, lg = lane >> 4;
    int n = blockIdx.x * 4 + w;
    const float* xg = x + (size_t)n * (CIN * WW);

    const half8* w1v = (const half8*)w1p;
    const half8* wgv = (const half8*)wgp;

    half8 av[2][8];
#pragma unroll
    for (int s = 0; s < 2; ++s)
#pragma unroll
        for (int mt = 0; mt < 8; ++mt)
            av[s][mt] = w1v[(s * 4 + lg) * 128 + mt * 16 + lc];
    half8 bw[2];
#pragma unroll
    for (int s2 = 0; s2 < 2; ++s2) bw[s2] = wgv[(s2 * 4 + lg) * 16 + lc];

    const float* xr0 = xg + (size_t)lg * WW;
    const float* xr1 = xg + (size_t)(4 + lg) * WW;
    bool cok1 = (4 + lg) < CIN;

    f32x4 acc2[4];
#pragma unroll
    for (int mt2 = 0; mt2 < 4; ++mt2) acc2[mt2] = (f32x4)0.0f;

#pragma unroll
    for (int nt = 0; nt < 4; ++nt) {
        int t = nt * 16 + lc;
        half8 bf0, bf1;
#pragma unroll
        for (int e = 0; e < 8; ++e) {
            int tp = t + e;
            bf0[e] = (_Float16)((tp < WW) ? xr0[tp] : 0.0f);
            bf1[e] = (_Float16)((cok1 && tp < WW) ? xr1[tp] : 0.0f);
        }
        f32x4 acc[8];
#pragma unroll
        for (int mt = 0; mt < 8; ++mt) acc[mt] = (f32x4)0.0f;
#pragma unroll
        for (int mt = 0; mt < 8; ++mt)
            acc[mt] = __builtin_amdgcn_mfma_f32_16x16x32_f16(av[0][mt], bf0,
                                                             acc[mt], 0, 0, 0);
#pragma unroll
        for (int mt = 0; mt < 8; ++mt)
            acc[mt] = __builtin_amdgcn_mfma_f32_16x16x32_f16(av[1][mt], bf1,
                                                             acc[mt], 0, 0, 0);
        half4 h4[4];
#pragma unroll
        for (int mtp = 0; mtp < 4; ++mtp) {
            int cb = 32 * (mtp >> 1) + 8 * lg + 4 * (mtp & 1);
            float4 bP = *(const float4*)(b1 + cb);
            float4 bQ = *(const float4*)(b1 + 64 + cb);
            f32x4 P = acc[mtp];
            f32x4 Q = acc[mtp + 4];
            half4 hh;
            hh[0] = (_Float16)((P[0] + bP.x) * (1.0f / (1.0f + __expf(-(Q[0] + bQ.x)))));
            hh[1] = (_Float16)((P[1] + bP.y) * (1.0f / (1.0f + __expf(-(Q[1] + bQ.y)))));
            hh[2] = (_Float16)((P[2] + bP.z) * (1.0f / (1.0f + __expf(-(Q[2] + bQ.z)))));
            hh[3] = (_Float16)((P[3] + bP.w) * (1.0f / (1.0f + __expf(-(Q[3] + bQ.w)))));
            h4[mtp] = hh;
        }
#pragma unroll
        for (int s2 = 0; s2 < 2; ++s2) {
            half8 af = __builtin_shufflevector(h4[2 * s2], h4[2 * s2 + 1],
                                               0, 1, 2, 3, 4, 5, 6, 7);
            acc2[nt] = __builtin_amdgcn_mfma_f32_16x16x32_f16(af, bw[s2],
                                                              acc2[nt], 0, 0, 0);
        }
    }

    _Float16* xtn = xt + (size_t)n * FT;
#pragma unroll
    for (int mt2 = 0; mt2 < 4; ++mt2) {
#pragma unroll
        for (int j = 0; j < 4; ++j) {
            int t = mt2 * 16 + 4 * lg + j;
            if (t < T1) xtn[t * 16 + lc] = (_Float16)acc2[mt2][j];
        }
    }
}

// ---------------------------------------------------------------------------
// Fused gather + conv2. Wave = 1 node, fully independent (no barriers).
// Gather: f16 xt loads (2x half8/lane), f32 accum, 2-deep software pipeline.
// gs: per-wave f16 [f][t] stride 58. conv2 B-frags straight from global w2p.
// Epilogue: stage each ntp-chunk (16 cols x 50 t, 3200B) in wave-private LDS,
// then write back as fully coalesced, line-aligned nontemporal float4 streams
// (row stride 200B is not sector-aligned -> direct stores cost 2x HBM write).
__global__ __launch_bounds__(256, 4) void k_gc2(
        const _Float16* __restrict__ xt, const float* __restrict__ deg,
        const int* __restrict__ offs, const int2* __restrict__ em,
        const float* __restrict__ bg, const _Float16* __restrict__ w2p,
        const float* __restrict__ b2, float* __restrict__ out) {
    __shared__ _Float16 gs[4][952];              // [16][58] + pad, 7616 B total
    __shared__ __align__(16) float gout[4][16 * T2];  // 3200 B per wave
    int tid = threadIdx.x;
    int w = tid >> 6, lane = tid & 63;
    int lc = lane & 15, lg = lane >> 4;
    int n = blockIdx.x * 4 + w;
    bool hi = lane < 50;                // second half8 covers elems 512..911

    float dc = rsqrtf(deg[n] + 1.0f);
    float a0[8], a1[8];
    {
        const half8* xs = (const half8*)(xt + (size_t)n * FT);
        half8 u0 = xs[lane];
        half8 u1 = (half8)(_Float16)0.0f;
        if (hi) u1 = xs[64 + lane];
        float sw = dc * dc;
#pragma unroll
        for (int j = 0; j < 8; ++j) {
            a0[j] = (float)u0[j] * sw;
            a1[j] = (float)u1[j] * sw;
        }
    }
    int beg = offs[n];
    int m = offs[n + 1] - beg;
    int2 rw0 = make_int2(0, 0), rw1 = make_int2(0, 0);
    half8 c0 = (half8)(_Float16)0.0f, c1 = (half8)(_Float16)0.0f;
    if (m > 0) {
        rw0 = em[beg];
        const half8* xr = (const half8*)(xt + (size_t)rw0.x * FT);
        c0 = xr[lane];
        if (hi) c1 = xr[64 + lane];
    }
    if (m > 1) rw1 = em[beg + 1];
    for (int i = 0; i < m; ++i) {
        float wv = __int_as_float(rw0.y) * dc;
        half8 d0 = c0, d1 = c1;
        int2 rwn = (i + 2 < m) ? em[beg + i + 2] : rw1;
        if (i + 1 < m) {
            const half8* xr = (const half8*)(xt + (size_t)rw1.x * FT);
            c0 = xr[lane];
            c1 = (half8)(_Float16)0.0f;
            if (hi) c1 = xr[64 + lane];
        }
        rw0 = rw1; rw1 = rwn;
#pragma unroll
        for (int j = 0; j < 8; ++j) {
            a0[j] += (float)d0[j] * wv;
            a1[j] += (float)d1[j] * wv;
        }
    }

    // relu + bias -> gs[f][t] (f16, stride 58). Lane owns f=(lane&1)*8+j,
    // t = lane>>1 (a0) and 32+(lane>>1) (a1, lanes<50).
    {
        _Float16* g = gs[w];
        int f0 = (lane & 1) * 8;
        int t0 = lane >> 1;
        float4 bgA = *(const float4*)(bg + f0);
        float4 bgB = *(const float4*)(bg + f0 + 4);
        float bv[8] = {bgA.x, bgA.y, bgA.z, bgA.w, bgB.x, bgB.y, bgB.z, bgB.w};
#pragma unroll
        for (int j = 0; j < 8; ++j) {
            g[(f0 + j) * 58 + t0] = (_Float16)fmaxf(a0[j] + bv[j], 0.0f);
            if (hi) g[(f0 + j) * 58 + 32 + t0] = (_Float16)fmaxf(a1[j] + bv[j], 0.0f);
        }
    }
    // wave-private LDS region: compiler orders write->read via lgkmcnt,
    // no __syncthreads needed (waves fully independent).

    const _Float16* g = gs[w];
    half8 af[4][4];
#pragma unroll
    for (int s = 0; s < 4; ++s)
#pragma unroll
        for (int mt = 0; mt < 4; ++mt) {
            int tb = mt * 16 + lc + 2 * s;
            half8 v;
#pragma unroll
            for (int j = 0; j < 4; ++j) {
                int ci = lg * 4 + j;
                v[2 * j]     = g[ci * 58 + tb];
                v[2 * j + 1] = g[ci * 58 + tb + 1];
            }
            af[s][mt] = v;
        }

    const half8* wsv = (const half8*)w2p;
    float* outn = out + (size_t)n * (H1C * T2);
    float* go = gout[w];
#pragma unroll
    for (int ntp = 0; ntp < 4; ++ntp) {
        f32x4 aP[4], aQ[4];
#pragma unroll
        for (int mt = 0; mt < 4; ++mt) { aP[mt] = (f32x4)0.0f; aQ[mt] = (f32x4)0.0f; }
#pragma unroll
        for (int s = 0; s < 4; ++s) {
            half8 bP = wsv[(s * 4 + lg) * 128 + ntp * 16 + lc];
            half8 bQ = wsv[(s * 4 + lg) * 128 + (ntp + 4) * 16 + lc];
#pragma unroll
            for (int mt = 0; mt < 4; ++mt) {
                aP[mt] = __builtin_amdgcn_mfma_f32_16x16x32_f16(af[s][mt], bP,
                                                                aP[mt], 0, 0, 0);
                aQ[mt] = __builtin_amdgcn_mfma_f32_16x16x32_f16(af[s][mt], bQ,
                                                                aQ[mt], 0, 0, 0);
            }
        }
        int c = ntp * 16 + lc;
        float bp = b2[c], bq = b2[64 + c];
        // stage [lc][t<50] into wave-private LDS (column-major rows of 50)
#pragma unroll
        for (int mt = 0; mt < 4; ++mt) {
#pragma unroll
            for (int e2 = 0; e2 < 4; ++e2) {
                int t = mt * 16 + lg * 4 + e2;
                if (t < T2) {
                    float vv = (aP[mt][e2] + bp) *
                               (1.0f / (1.0f + __expf(-(aQ[mt][e2] + bq))));
                    go[lc * T2 + t] = vv;
                }
            }
        }
        // coalesced nontemporal writeback: 800 floats = 3x1024B + 128B
        float* dst = outn + ntp * (16 * T2);
#pragma unroll
        for (int i = 0; i < 3; ++i) {
            f32x4 v = *(const f32x4*)(go + i * 256 + lane * 4);
            __builtin_nontemporal_store(v, (f32x4*)(dst + i * 256 + lane * 4));
        }
        if (lane < 8) {
            f32x4 v = *(const f32x4*)(go + 768 + lane * 4);
            __builtin_nontemporal_store(v, (f32x4*)(dst + 768 + lane * 4));
        }
    }
}

// ---------------------------------------------------------------------------
extern "C" void kernel_launch(void* const* d_in, const int* in_sizes, int n_in,
                              void* d_out, int out_size, void* d_ws, size_t ws_size,
                              hipStream_t stream) {
    const float* x   = (const float*)d_in[0];
    const int*   ei  = (const int*)d_in[1];
    const float* ea  = (const float*)d_in[2];
    const float* Wc1 = (const float*)d_in[4];
    const float* b1  = (const float*)d_in[5];
    const float* Wg  = (const float*)d_in[6];
    const float* bg  = (const float*)d_in[7];
    const float* Wc2 = (const float*)d_in[8];
    const float* b2  = (const float*)d_in[9];
    float* out = (float*)d_out;

    char* ws = (char*)d_ws;
    size_t off = 0;
    auto alloc = [&](size_t bytes) -> void* {
        void* p = ws + off;
        off += (bytes + 255) & ~(size_t)255;
        return p;
    };
    int*      flag   = (int*)alloc(4);
    float*    deg    = (float*)alloc((size_t)NN * 4);
    int*      cnt    = (int*)alloc((size_t)NN * 4);
    int*      offs   = (int*)alloc((size_t)(NN + 1) * 4);
    int*      cursor = (int*)alloc((size_t)NN * 4);
    int2*     em     = (int2*)alloc((size_t)EE * 8);
    _Float16* xt     = (_Float16*)alloc((size_t)NN * FT * 2);
    _Float16* w2p    = (_Float16*)alloc((size_t)16384 * 2);
    _Float16* w1p    = (_Float16*)alloc((size_t)8192 * 2);
    _Float16* wgp    = (_Float16*)alloc((size_t)1024 * 2);
    (void)ws_size; (void)in_sizes; (void)n_in; (void)out_size;

    hipMemsetAsync(deg, 0, (size_t)NN * 4, stream);
    hipMemsetAsync(cnt, 0, (size_t)NN * 4, stream);
    k_detect<<<1, 64, 0, stream>>>(ei, flag);
    k_deg_prep<<<EE / 256 + 100, 256, 0, stream>>>(ei, flag, ea, deg, cnt,
                                                   Wc2, w2p, Wc1, w1p, Wg, wgp);
    k_scan<<<1, 1024, 0, stream>>>(cnt, offs, cursor);
    k_fill<<<EE / 256, 256, 0, stream>>>(ei, flag, ea, deg, cursor, em);
    k_conv1<<<NN / 4, 256, 0, stream>>>(x, w1p, b1, wgp, xt);
    k_gc2<<<NN / 4, 256, 0, stream>>>(xt, deg, offs, em, bg, w2p, b2, out);
}